// Round 14
// baseline (418.063 us; speedup 1.0000x reference)
//
#include <hip/hip_runtime.h>
#include <hip/hip_bf16.h>

// S=2048, E=2048, H=16, D=128
#define S_LEN 2048
#define EMB   2048
#define NH    16
#define HD    128

typedef __bf16 bf16x8 __attribute__((ext_vector_type(8)));
typedef __bf16 bf16x4 __attribute__((ext_vector_type(4)));
typedef float  f32x4  __attribute__((ext_vector_type(4)));
typedef short  s16x4  __attribute__((ext_vector_type(4)));

__device__ __forceinline__ void async_copy16(void* lds, const void* g) {
  __builtin_amdgcn_global_load_lds((__attribute__((address_space(1))) void*)(void*)g,
                                   (__attribute__((address_space(3))) void*)lds, 16, 0, 0);
}

__device__ __forceinline__ unsigned lds_addr(const void* p) {
  return (unsigned)(uintptr_t)(const __attribute__((address_space(3))) char*)p;
}

__device__ __forceinline__ s16x4 tr16(unsigned addr) {
  s16x4 d;
  asm volatile("ds_read_b64_tr_b16 %0, %1" : "=v"(d) : "v"(addr));
  return d;
}

__device__ __forceinline__ float gelu_tanh(float x) {
  float x3 = x * x * x;
  float t  = 0.7978845608028654f * (x + 0.044715f * x3);
  float th = 1.0f - 2.0f / (__expf(2.0f * t) + 1.0f);
  return 0.5f * x * (1.0f + th);
}

// ---------------- fp32 -> bf16 cast (weights) ----------------
__global__ __launch_bounds__(256) void cast_kernel(const float* __restrict__ in,
                                                   __bf16* __restrict__ out, int n) {
  int i = (blockIdx.x * 256 + threadIdx.x) * 4;
  if (i >= n) return;
  float4 v = *(const float4*)(in + i);
  bf16x4 o;
  o[0] = (__bf16)v.x; o[1] = (__bf16)v.y; o[2] = (__bf16)v.z; o[3] = (__bf16)v.w;
  *(bf16x4*)(out + i) = o;
}

// ---------------- LayerNorm (LN1) ----------------
__global__ __launch_bounds__(256) void ln_kernel(const float* __restrict__ x,
                                                 const float* __restrict__ w,
                                                 __bf16* __restrict__ out) {
  int row = blockIdx.x;
  int t = threadIdx.x;
  const float* xr = x + (size_t)row * EMB;
  float4 a = *(const float4*)(xr + t * 8);
  float4 b = *(const float4*)(xr + t * 8 + 4);
  float s  = a.x + a.y + a.z + a.w + b.x + b.y + b.z + b.w;
  float sq = a.x*a.x + a.y*a.y + a.z*a.z + a.w*a.w + b.x*b.x + b.y*b.y + b.z*b.z + b.w*b.w;
  #pragma unroll
  for (int o = 32; o > 0; o >>= 1) { s += __shfl_xor(s, o); sq += __shfl_xor(sq, o); }
  __shared__ float red[8];
  if ((t & 63) == 0) { red[t >> 6] = s; red[(t >> 6) + 4] = sq; }
  __syncthreads();
  s  = red[0] + red[1] + red[2] + red[3];
  sq = red[4] + red[5] + red[6] + red[7];
  float mu  = s * (1.0f / EMB);
  float var = sq * (1.0f / EMB) - mu * mu;
  float rs  = rsqrtf(var + 1e-5f);
  float4 w1 = *(const float4*)(w + t * 8);
  float4 w2 = *(const float4*)(w + t * 8 + 4);
  bf16x8 ov;
  ov[0] = (__bf16)((a.x - mu) * rs * w1.x);
  ov[1] = (__bf16)((a.y - mu) * rs * w1.y);
  ov[2] = (__bf16)((a.z - mu) * rs * w1.z);
  ov[3] = (__bf16)((a.w - mu) * rs * w1.w);
  ov[4] = (__bf16)((b.x - mu) * rs * w2.x);
  ov[5] = (__bf16)((b.y - mu) * rs * w2.y);
  ov[6] = (__bf16)((b.z - mu) * rs * w2.z);
  ov[7] = (__bf16)((b.w - mu) * rs * w2.w);
  *(bf16x8*)(out + (size_t)row * EMB + t * 8) = ov;
}

// ---------------- LN2 fused with proj1 split-K reduce + residual ----------------
__global__ __launch_bounds__(256) void ln_fuse_kernel(const float* __restrict__ x,
                                                      const __bf16* __restrict__ part,
                                                      const float* __restrict__ w,
                                                      __bf16* __restrict__ hout,
                                                      float* __restrict__ resout) {
  int row = blockIdx.x;
  int t = threadIdx.x;
  const size_t base = (size_t)row * EMB + t * 8;
  float r[8];
  {
    float4 a = *(const float4*)(x + base);
    float4 b = *(const float4*)(x + base + 4);
    r[0] = a.x; r[1] = a.y; r[2] = a.z; r[3] = a.w;
    r[4] = b.x; r[5] = b.y; r[6] = b.z; r[7] = b.w;
    #pragma unroll
    for (int z = 0; z < 4; z++) {
      bf16x8 p = *(const bf16x8*)(part + (size_t)z * S_LEN * EMB + base);
      #pragma unroll
      for (int k = 0; k < 8; k++) r[k] += (float)p[k];
    }
  }
  float s = 0.f, sq = 0.f;
  #pragma unroll
  for (int k = 0; k < 8; k++) { s += r[k]; sq += r[k] * r[k]; }
  #pragma unroll
  for (int o = 32; o > 0; o >>= 1) { s += __shfl_xor(s, o); sq += __shfl_xor(sq, o); }
  __shared__ float red[8];
  if ((t & 63) == 0) { red[t >> 6] = s; red[(t >> 6) + 4] = sq; }
  __syncthreads();
  s  = red[0] + red[1] + red[2] + red[3];
  sq = red[4] + red[5] + red[6] + red[7];
  float mu  = s * (1.0f / EMB);
  float var = sq * (1.0f / EMB) - mu * mu;
  float rs  = rsqrtf(var + 1e-5f);
  float4 w1 = *(const float4*)(w + t * 8);
  float4 w2 = *(const float4*)(w + t * 8 + 4);
  float wv[8] = {w1.x, w1.y, w1.z, w1.w, w2.x, w2.y, w2.z, w2.w};
  bf16x8 ov;
  #pragma unroll
  for (int k = 0; k < 8; k++) ov[k] = (__bf16)((r[k] - mu) * rs * wv[k]);
  *(bf16x8*)(hout + base) = ov;
  float4 o1 = make_float4(r[0], r[1], r[2], r[3]);
  float4 o2 = make_float4(r[4], r[5], r[6], r[7]);
  *(float4*)(resout + base) = o1;
  *(float4*)(resout + base + 4) = o2;
}

// ---------------- proj2 reduce: out += sum_z part[z] ----------------
__global__ __launch_bounds__(256) void add4_kernel(float* __restrict__ out,
                                                   const __bf16* __restrict__ part) {
  size_t i = ((size_t)blockIdx.x * 256 + threadIdx.x) * 4;
  float4 o = *(const float4*)(out + i);
  #pragma unroll
  for (int z = 0; z < 4; z++) {
    bf16x4 p = *(const bf16x4*)(part + (size_t)z * S_LEN * EMB + i);
    o.x += (float)p[0]; o.y += (float)p[1]; o.z += (float)p[2]; o.w += (float)p[3];
  }
  *(float4*)(out + i) = o;
}

// ---------------- 128x256 GEMM, BK=32, ring-3 LDS, 2 blocks/CU ----------------
// 512 threads = 8 waves (2M x 4N), per-wave 64x64 (R3-verified fragment geometry).
// LDS = 3 slots x (A 8KB + B 16KB) = 72 KB -> 2 blocks/CU co-resident (m114 overlap).
// One phase per K-tile: { ds_read frags(slot kt%3); stage tile kt+2 -> slot (kt+2)%3;
// setprio(1) 16 MFMA setprio(0); vmcnt(3|0); s_barrier }. Ledger: slot s2's last
// reader finished before the previous barrier; fresh slot published by all-waves
// vmcnt + this barrier. Swizzle: granule ^= (row>>1)&3 both sides (0 conflicts).
// EPI: 0 = store bf16; 2 = gelu bf16; 5 = bf16 partial at slice z.
template <int EPI>
__global__ __launch_bounds__(512, 4) void gemm128(const __bf16* __restrict__ A,
                                                  const __bf16* __restrict__ B,
                                                  void* __restrict__ Cv,
                                                  int M, int N, int K, int Ksl,
                                                  int NN, int NSPLIT) {
  __shared__ __bf16 As[3][128 * 32];   // 8 KB / slot
  __shared__ __bf16 Bs[3][256 * 32];   // 16 KB / slot

  const int t = threadIdx.x, w = t >> 6, l = t & 63;
  const int fr = l & 15, g = l >> 4;
  const int wr = w >> 2, wc = w & 3;      // per-wave 64 rows x 64 cols

  // XCD-bijective block swizzle (nwg % 8 == 0 at all call sites); z innermost
  const int nwg = gridDim.x;
  const int wg = (blockIdx.x & 7) * (nwg >> 3) + (blockIdx.x >> 3);
  const int z = wg % NSPLIT;
  const int tile = wg / NSPLIT;
  const int my = tile / NN, nx = tile - my * NN;
  const int m0 = my * 128, n0 = nx * 256;
  const int kb = z * Ksl;
  const int NT = Ksl >> 5;                // BK = 32 (NT >= 16 at all call sites)

  // staging: A chunk t -> row t>>2, phys granule t&3; B chunks t and t+512
  // source granule = phys ^ ((row>>1)&3) = (t&3) ^ ((t>>3)&3)  (row+128 preserves it)
  const int srow = t >> 2;
  const int schunk = (t & 3) ^ ((t >> 3) & 3);
  const __bf16* Abase = A + (size_t)(m0 + srow) * K + kb + schunk * 8;
  const __bf16* Bbase = B + (size_t)(n0 + srow) * K + kb + schunk * 8;
  const size_t K128 = (size_t)128 * K;

  auto stage = [&](int kt, int slot) {   // 3 loads
    const __bf16* sa = Abase + kt * 32;
    const __bf16* sb = Bbase + kt * 32;
    async_copy16(&As[slot][t * 8], sa);
    async_copy16(&Bs[slot][t * 8], sb);
    async_copy16(&Bs[slot][t * 8 + 4096], sb + K128);
  };

  // fragment reads: logical granule g at row r -> phys granule g ^ ((fr>>1)&3)
  const int gran = (g ^ ((fr >> 1) & 3)) << 3;

  f32x4 acc[4][4] = {};

  // prologue: stage tiles 0,1 (6 loads); confirm tile 0 (3 newest remain)
  stage(0, 0);
  stage(1, 1);
  asm volatile("s_waitcnt vmcnt(3)" ::: "memory");
  __builtin_amdgcn_s_barrier();

  int sc = 0, s1 = 1, s2 = 2;
  for (int kt = 0; kt < NT; ++kt) {
    bf16x8 a[4], b[4];
    #pragma unroll
    for (int m = 0; m < 4; m++)
      a[m] = *(const bf16x8*)&As[sc][(wr * 64 + m * 16 + fr) * 32 + gran];
    #pragma unroll
    for (int n = 0; n < 4; n++)
      b[n] = *(const bf16x8*)&Bs[sc][(wc * 64 + n * 16 + fr) * 32 + gran];
    if (kt + 2 < NT) stage(kt + 2, s2);
    __builtin_amdgcn_s_setprio(1);
    #pragma unroll
    for (int m = 0; m < 4; m++)
      #pragma unroll
      for (int n = 0; n < 4; n++)
        acc[m][n] = __builtin_amdgcn_mfma_f32_16x16x32_bf16(a[m], b[n], acc[m][n], 0, 0, 0);
    __builtin_amdgcn_s_setprio(0);
    if (kt + 1 < NT) {
      if (kt + 2 < NT) { asm volatile("s_waitcnt vmcnt(3)" ::: "memory"); }
      else             { asm volatile("s_waitcnt vmcnt(0)" ::: "memory"); }
    }
    __builtin_amdgcn_s_barrier();
    int tmp = sc; sc = s1; s1 = s2; s2 = tmp;
  }

  const size_t zoff = (size_t)z * M * N;
  #pragma unroll
  for (int m = 0; m < 4; m++)
    #pragma unroll
    for (int n = 0; n < 4; n++)
      #pragma unroll
      for (int j = 0; j < 4; j++) {
        int orow = m0 + wr * 64 + m * 16 + g * 4 + j;
        int ocol = n0 + wc * 64 + n * 16 + fr;
        size_t idx = (size_t)orow * N + ocol;
        float v = acc[m][n][j];
        if (EPI == 0) {
          ((__bf16*)Cv)[idx] = (__bf16)v;
        } else if (EPI == 2) {
          ((__bf16*)Cv)[idx] = (__bf16)gelu_tanh(v);
        } else {
          ((__bf16*)Cv)[zoff + idx] = (__bf16)v;
        }
      }
}

// ---------------- Flash attention (causal), paired q-tiles, 8 waves (R13) ----------------
__global__ __launch_bounds__(512, 2) void attn_kernel(const __bf16* __restrict__ qkv,
                                                      __bf16* __restrict__ out) {
  __shared__ __bf16 Kt[2][64 * 128];
  __shared__ __bf16 Vt[2][64 * 128];
  __shared__ __bf16 Pb[8][16 * 64];

  const int bid = blockIdx.x;
  const int h = bid & 15;
  const int pi = bid >> 4;
  const int qbA = pi, qbB = 31 - pi;

  const int t = threadIdx.x, w = t >> 6, l = t & 63;
  const int g = l >> 4, fr = l & 15;
  const int fkb = g * 8;
  const int myqb = (w < 4) ? qbA : qbB;
  const int q0 = myqb * 64 + (w & 3) * 16;
  const float scale = 0.08838834764831845f; // 1/sqrt(128)

  const int kchunk = fr ^ ((w * 4 + g) & 7);
  const int vkey = (l >> 1) & 3;
  const int vd0  = (l >> 3) * 16 + (l & 1) * 8;

  const size_t row3E = (size_t)(3 * EMB);
  const __bf16* Kg = qkv + EMB + h * HD;
  const __bf16* Vg = qkv + 2 * EMB + h * HD;

  bf16x8 qf[4];
  #pragma unroll
  for (int kc = 0; kc < 4; kc++)
    qf[kc] = *(const bf16x8*)&qkv[(size_t)(q0 + fr) * row3E + h * HD + kc * 32 + fkb];

  f32x4 o[8] = {};
  float mrun[4] = {-1e30f, -1e30f, -1e30f, -1e30f};
  float lsum[4] = {0.f, 0.f, 0.f, 0.f};

  const unsigned vtrb[2] = { lds_addr(&Vt[0][0]) + g * 2048 + fr * 8,
                             lds_addr(&Vt[1][0]) + g * 2048 + fr * 8 };

  auto stage = [&](int buf, int it) {
    const int t0 = it * 64;
    #pragma unroll
    for (int r = 0; r < 2; r++) {
      async_copy16(&Kt[buf][(r * 8 + w) * 512],
                   Kg + (size_t)(t0 + (r * 8 + w) * 4 + g) * row3E + kchunk * 8);
      async_copy16(&Vt[buf][(r * 8 + w) * 512],
                   Vg + (size_t)(t0 + (r * 8 + w) * 4 + vkey) * row3E + vd0);
    }
  };

  const int nt = qbB + 1;
  stage(0, 0);
  int cur = 0;

  for (int it = 0; it < nt; it++) {
    __syncthreads();
    if (it + 1 < nt) stage(cur ^ 1, it + 1);

    if (it <= myqb) {
      const int t0 = it * 64;
      f32x4 s[4] = {};
      __builtin_amdgcn_s_setprio(1);
      #pragma unroll
      for (int n = 0; n < 4; n++)
        #pragma unroll
        for (int kc = 0; kc < 4; kc++) {
          bf16x8 kf = *(const bf16x8*)&Kt[cur][(n * 16 + fr) * 128 +
                                              (((kc * 4 + g) ^ (fr & 7)) << 3)];
          s[n] = __builtin_amdgcn_mfma_f32_16x16x32_bf16(qf[kc], kf, s[n], 0, 0, 0);
        }
      __builtin_amdgcn_s_setprio(0);
      #pragma unroll
      for (int n = 0; n < 4; n++)
        #pragma unroll
        for (int j = 0; j < 4; j++) {
          int tcol = t0 + n * 16 + fr;
          int qrow = q0 + g * 4 + j;
          float v = s[n][j] * scale;
          s[n][j] = (tcol > qrow) ? -1e30f : v;
        }
      float pm[4];
      #pragma unroll
      for (int j = 0; j < 4; j++) {
        pm[j] = fmaxf(fmaxf(s[0][j], s[1][j]), fmaxf(s[2][j], s[3][j]));
        #pragma unroll
        for (int off = 1; off < 16; off <<= 1) pm[j] = fmaxf(pm[j], __shfl_xor(pm[j], off));
      }
      float factor[4];
      #pragma unroll
      for (int j = 0; j < 4; j++) {
        float mn = fmaxf(mrun[j], pm[j]);
        factor[j] = __expf(mrun[j] - mn);
        mrun[j] = mn;
      }
      float rs[4] = {0.f, 0.f, 0.f, 0.f};
      #pragma unroll
      for (int n = 0; n < 4; n++)
        #pragma unroll
        for (int j = 0; j < 4; j++) {
          float p = __expf(s[n][j] - mrun[j]);
          s[n][j] = p;
          rs[j] += p;
        }
      #pragma unroll
      for (int j = 0; j < 4; j++) {
        #pragma unroll
        for (int off = 1; off < 16; off <<= 1) rs[j] += __shfl_xor(rs[j], off);
        lsum[j] = lsum[j] * factor[j] + rs[j];
      }
      #pragma unroll
      for (int b = 0; b < 8; b++)
        #pragma unroll
        for (int j = 0; j < 4; j++) o[b][j] *= factor[j];

      #pragma unroll
      for (int n = 0; n < 4; n++)
        #pragma unroll
        for (int j = 0; j < 4; j++) {
          int q   = g * 4 + j;
          int key = n * 16 + fr;
          int cs  = (key >> 3) ^ (q & 7);
          Pb[w][q * 64 + cs * 8 + (key & 7)] = (__bf16)s[n][j];
        }

      bf16x8 pf[2];
      #pragma unroll
      for (int kc = 0; kc < 2; kc++)
        pf[kc] = *(const bf16x8*)&Pb[w][fr * 64 + (((kc * 4 + g) ^ (fr & 7)) << 3)];

      const unsigned vtr = vtrb[cur];
      __builtin_amdgcn_s_setprio(1);
      #pragma unroll
      for (int b = 0; b < 8; b++) {
        s16x4 t00 = tr16(vtr + b * 128);
        s16x4 t01 = tr16(vtr + b * 128 + 1024);
        s16x4 t10 = tr16(vtr + b * 128 + 8192);
        s16x4 t11 = tr16(vtr + b * 128 + 8192 + 1024);
        asm volatile("s_waitcnt lgkmcnt(0)");
        __builtin_amdgcn_sched_barrier(0);
        union { s16x4 hh[2]; bf16x8 v; } u0, u1;
        u0.hh[0] = t00; u0.hh[1] = t01;
        u1.hh[0] = t10; u1.hh[1] = t11;
        o[b] = __builtin_amdgcn_mfma_f32_16x16x32_bf16(pf[0], u0.v, o[b], 0, 0, 0);
        o[b] = __builtin_amdgcn_mfma_f32_16x16x32_bf16(pf[1], u1.v, o[b], 0, 0, 0);
      }
      __builtin_amdgcn_s_setprio(0);
    }
    cur ^= 1;
  }

  float rcp[4];
  #pragma unroll
  for (int j = 0; j < 4; j++) rcp[j] = 1.0f / lsum[j];
  #pragma unroll
  for (int b = 0; b < 8; b++)
    #pragma unroll
    for (int j = 0; j < 4; j++) {
      int qrow = q0 + g * 4 + j;
      out[(size_t)qrow * EMB + h * HD + b * 16 + fr] = (__bf16)(o[b][j] * rcp[j]);
    }
}

// ---------------- launch ----------------
extern "C" void kernel_launch(void* const* d_in, const int* in_sizes, int n_in,
                              void* d_out, int out_size, void* d_ws, size_t ws_size,
                              hipStream_t stream) {
  const float* x     = (const float*)d_in[0];
  const float* ln1w  = (const float*)d_in[1];
  const float* ln2w  = (const float*)d_in[2];
  const float* wattn = (const float*)d_in[3];
  const float* wproja= (const float*)d_in[4];
  const float* wfc   = (const float*)d_in[5];
  const float* wprojf= (const float*)d_in[6];
  float* out = (float*)d_out;
  char* ws = (char*)d_ws;

  __bf16* wattn_b  = (__bf16*)(ws);                 // 3E*E bf16 = 24 MB
  __bf16* wproja_b = (__bf16*)(ws + 25165824);      // E*E
  __bf16* wfc_b    = (__bf16*)(ws + 33554432);      // 4E*E
  __bf16* wprojf_b = (__bf16*)(ws + 67108864);      // E*4E
  __bf16* h_b      = (__bf16*)(ws + 100663296);     // S*E
  __bf16* qkv_b    = (__bf16*)(ws + 109051904);     // S*3E
  __bf16* attn_b   = (__bf16*)(ws + 134217728);     // S*E
  __bf16* f1_b     = (__bf16*)(ws + 142606336);     // S*4E (33.5 MB)
  __bf16* p1_part  = f1_b;      // proj1 partials: dead before FC writes f1
  __bf16* p2_part  = qkv_b;     // proj2 partials: qkv dead by then

  cast_kernel<<<12288, 256, 0, stream>>>(wattn,  wattn_b,  12582912);
  cast_kernel<<<4096,  256, 0, stream>>>(wproja, wproja_b, 4194304);
  cast_kernel<<<16384, 256, 0, stream>>>(wfc,    wfc_b,    16777216);
  cast_kernel<<<16384, 256, 0, stream>>>(wprojf, wprojf_b, 16777216);

  ln_kernel<<<S_LEN, 256, 0, stream>>>(x, ln1w, h_b);
  // QKV: [2048, 6144], tiles 16x24 = 384 blocks
  gemm128<0><<<384, 512, 0, stream>>>(h_b, wattn_b, qkv_b, S_LEN, 3 * EMB, EMB, EMB, 24, 1);
  attn_kernel<<<dim3(256), 512, 0, stream>>>(qkv_b, attn_b);
  // attn proj: split-K x4 -> bf16 partials, 16x8x4 = 512 blocks (Ksl=512, NT=16)
  gemm128<5><<<512, 512, 0, stream>>>(attn_b, wproja_b, p1_part, S_LEN, EMB, EMB, EMB / 4, 8, 4);
  // LN2 fused with partial reduce + residual: h_b (bf16), out = res1 (f32)
  ln_fuse_kernel<<<S_LEN, 256, 0, stream>>>(x, p1_part, ln2w, h_b, out);
  // FC + GELU: [2048, 8192], tiles 16x32 = 512 blocks
  gemm128<2><<<512, 512, 0, stream>>>(h_b, wfc_b, f1_b, S_LEN, 4 * EMB, EMB, EMB, 32, 1);
  // FFN proj: split-K x4 -> bf16 partials, 16x8x4 = 512 blocks (Ksl=2048, NT=64)
  gemm128<5><<<512, 512, 0, stream>>>(f1_b, wprojf_b, p2_part, S_LEN, EMB, 4 * EMB, 2048, 8, 4);
  // out += sum of partials
  add4_kernel<<<4096, 256, 0, stream>>>(out, p2_part);
}

// Round 15
// 413.651 us; speedup vs baseline: 1.0107x; 1.0107x over previous
//
#include <hip/hip_runtime.h>
#include <hip/hip_bf16.h>

// S=2048, E=2048, H=16, D=128
#define S_LEN 2048
#define EMB   2048
#define NH    16
#define HD    128

typedef __bf16 bf16x8 __attribute__((ext_vector_type(8)));
typedef __bf16 bf16x4 __attribute__((ext_vector_type(4)));
typedef float  f32x4  __attribute__((ext_vector_type(4)));
typedef short  s16x4  __attribute__((ext_vector_type(4)));

__device__ __forceinline__ void async_copy16(void* lds, const void* g) {
  __builtin_amdgcn_global_load_lds((__attribute__((address_space(1))) void*)(void*)g,
                                   (__attribute__((address_space(3))) void*)lds, 16, 0, 0);
}

__device__ __forceinline__ unsigned lds_addr(const void* p) {
  return (unsigned)(uintptr_t)(const __attribute__((address_space(3))) char*)p;
}

__device__ __forceinline__ s16x4 tr16(unsigned addr) {
  s16x4 d;
  asm volatile("ds_read_b64_tr_b16 %0, %1" : "=v"(d) : "v"(addr));
  return d;
}

__device__ __forceinline__ float gelu_tanh(float x) {
  float x3 = x * x * x;
  float t  = 0.7978845608028654f * (x + 0.044715f * x3);
  float th = 1.0f - 2.0f / (__expf(2.0f * t) + 1.0f);
  return 0.5f * x * (1.0f + th);
}

// ---------------- fp32 -> bf16 cast, all 4 weights in one launch ----------------
// Segment sizes are multiples of 1024 elements, so each 1024-elem block is segment-pure.
__global__ __launch_bounds__(256) void cast_all(const float* __restrict__ s0,
                                                const float* __restrict__ s1,
                                                const float* __restrict__ s2,
                                                const float* __restrict__ s3,
                                                __bf16* __restrict__ d0,
                                                __bf16* __restrict__ d1,
                                                __bf16* __restrict__ d2,
                                                __bf16* __restrict__ d3) {
  size_t i = ((size_t)blockIdx.x * 256 + threadIdx.x) * 4;
  const float* s; __bf16* d; size_t off;
  if (i < 12582912ull)       { s = s0; d = d0; off = i; }
  else if (i < 16777216ull)  { s = s1; d = d1; off = i - 12582912ull; }
  else if (i < 33554432ull)  { s = s2; d = d2; off = i - 16777216ull; }
  else                       { s = s3; d = d3; off = i - 33554432ull; }
  float4 v = *(const float4*)(s + off);
  bf16x4 o;
  o[0] = (__bf16)v.x; o[1] = (__bf16)v.y; o[2] = (__bf16)v.z; o[3] = (__bf16)v.w;
  *(bf16x4*)(d + off) = o;
}

// ---------------- LayerNorm (LN1) ----------------
__global__ __launch_bounds__(256) void ln_kernel(const float* __restrict__ x,
                                                 const float* __restrict__ w,
                                                 __bf16* __restrict__ out) {
  int row = blockIdx.x;
  int t = threadIdx.x;
  const float* xr = x + (size_t)row * EMB;
  float4 a = *(const float4*)(xr + t * 8);
  float4 b = *(const float4*)(xr + t * 8 + 4);
  float s  = a.x + a.y + a.z + a.w + b.x + b.y + b.z + b.w;
  float sq = a.x*a.x + a.y*a.y + a.z*a.z + a.w*a.w + b.x*b.x + b.y*b.y + b.z*b.z + b.w*b.w;
  #pragma unroll
  for (int o = 32; o > 0; o >>= 1) { s += __shfl_xor(s, o); sq += __shfl_xor(sq, o); }
  __shared__ float red[8];
  if ((t & 63) == 0) { red[t >> 6] = s; red[(t >> 6) + 4] = sq; }
  __syncthreads();
  s  = red[0] + red[1] + red[2] + red[3];
  sq = red[4] + red[5] + red[6] + red[7];
  float mu  = s * (1.0f / EMB);
  float var = sq * (1.0f / EMB) - mu * mu;
  float rs  = rsqrtf(var + 1e-5f);
  float4 w1 = *(const float4*)(w + t * 8);
  float4 w2 = *(const float4*)(w + t * 8 + 4);
  bf16x8 ov;
  ov[0] = (__bf16)((a.x - mu) * rs * w1.x);
  ov[1] = (__bf16)((a.y - mu) * rs * w1.y);
  ov[2] = (__bf16)((a.z - mu) * rs * w1.z);
  ov[3] = (__bf16)((a.w - mu) * rs * w1.w);
  ov[4] = (__bf16)((b.x - mu) * rs * w2.x);
  ov[5] = (__bf16)((b.y - mu) * rs * w2.y);
  ov[6] = (__bf16)((b.z - mu) * rs * w2.z);
  ov[7] = (__bf16)((b.w - mu) * rs * w2.w);
  *(bf16x8*)(out + (size_t)row * EMB + t * 8) = ov;
}

// ---------------- LN2 fused with proj1 split-K reduce + residual ----------------
__global__ __launch_bounds__(256) void ln_fuse_kernel(const float* __restrict__ x,
                                                      const __bf16* __restrict__ part,
                                                      const float* __restrict__ w,
                                                      __bf16* __restrict__ hout,
                                                      float* __restrict__ resout) {
  int row = blockIdx.x;
  int t = threadIdx.x;
  const size_t base = (size_t)row * EMB + t * 8;
  float r[8];
  {
    float4 a = *(const float4*)(x + base);
    float4 b = *(const float4*)(x + base + 4);
    r[0] = a.x; r[1] = a.y; r[2] = a.z; r[3] = a.w;
    r[4] = b.x; r[5] = b.y; r[6] = b.z; r[7] = b.w;
    #pragma unroll
    for (int z = 0; z < 4; z++) {
      bf16x8 p = *(const bf16x8*)(part + (size_t)z * S_LEN * EMB + base);
      #pragma unroll
      for (int k = 0; k < 8; k++) r[k] += (float)p[k];
    }
  }
  float s = 0.f, sq = 0.f;
  #pragma unroll
  for (int k = 0; k < 8; k++) { s += r[k]; sq += r[k] * r[k]; }
  #pragma unroll
  for (int o = 32; o > 0; o >>= 1) { s += __shfl_xor(s, o); sq += __shfl_xor(sq, o); }
  __shared__ float red[8];
  if ((t & 63) == 0) { red[t >> 6] = s; red[(t >> 6) + 4] = sq; }
  __syncthreads();
  s  = red[0] + red[1] + red[2] + red[3];
  sq = red[4] + red[5] + red[6] + red[7];
  float mu  = s * (1.0f / EMB);
  float var = sq * (1.0f / EMB) - mu * mu;
  float rs  = rsqrtf(var + 1e-5f);
  float4 w1 = *(const float4*)(w + t * 8);
  float4 w2 = *(const float4*)(w + t * 8 + 4);
  float wv[8] = {w1.x, w1.y, w1.z, w1.w, w2.x, w2.y, w2.z, w2.w};
  bf16x8 ov;
  #pragma unroll
  for (int k = 0; k < 8; k++) ov[k] = (__bf16)((r[k] - mu) * rs * wv[k]);
  *(bf16x8*)(hout + base) = ov;
  float4 o1 = make_float4(r[0], r[1], r[2], r[3]);
  float4 o2 = make_float4(r[4], r[5], r[6], r[7]);
  *(float4*)(resout + base) = o1;
  *(float4*)(resout + base + 4) = o2;
}

// ---------------- proj2 reduce: out += sum_z part[z] ----------------
__global__ __launch_bounds__(256) void add4_kernel(float* __restrict__ out,
                                                   const __bf16* __restrict__ part) {
  size_t i = ((size_t)blockIdx.x * 256 + threadIdx.x) * 4;
  float4 o = *(const float4*)(out + i);
  #pragma unroll
  for (int z = 0; z < 4; z++) {
    bf16x4 p = *(const bf16x4*)(part + (size_t)z * S_LEN * EMB + i);
    o.x += (float)p[0]; o.y += (float)p[1]; o.z += (float)p[2]; o.w += (float)p[3];
  }
  *(float4*)(out + i) = o;
}

// ---------------- 256x256 8-phase GEMM (R13, used for QKV + proj1) ----------------
#define MFMA16(AV, BV, MG)                                                                   \
  _Pragma("unroll")                                                                          \
  for (int m = 0; m < 4; m++)                                                                \
    _Pragma("unroll")                                                                        \
    for (int n = 0; n < 4; n++)                                                              \
      acc[(MG) * 4 + m][n] =                                                                 \
          __builtin_amdgcn_mfma_f32_16x16x32_bf16(AV[m], BV[n], acc[(MG) * 4 + m][n], 0, 0, 0);

#define PHASE_TOP()                                                                          \
  __builtin_amdgcn_s_barrier();                                                              \
  __builtin_amdgcn_s_setprio(1);

#define PHASE_BOT()                                                                          \
  __builtin_amdgcn_s_setprio(0);                                                             \
  __builtin_amdgcn_s_barrier();

template <int EPI>
__global__ __launch_bounds__(512, 2) void gemm256(const __bf16* __restrict__ A,
                                                  const __bf16* __restrict__ B,
                                                  void* __restrict__ Cv,
                                                  int M, int N, int K, int Ksl,
                                                  int NN, int NSPLIT) {
  __shared__ __bf16 As[2 * 2 * 256 * 32];
  __shared__ __bf16 Bs[2 * 2 * 256 * 32];

  const int t = threadIdx.x, w = t >> 6, l = t & 63;
  const int fr = l & 15, g = l >> 4;
  const int wr = w >> 2, wc = w & 3;

  const int nwg = gridDim.x;
  const int wg = (blockIdx.x & 7) * (nwg >> 3) + (blockIdx.x >> 3);
  const int z = wg % NSPLIT;
  const int tile = wg / NSPLIT;
  const int my = tile / NN, nx = tile - my * NN;
  const int m0 = my * 256, n0 = nx * 256;
  const int kb = z * Ksl;
  const int NT = Ksl >> 6;

  const int srow = t >> 2;
  const int schunk = (t & 3) ^ ((t >> 3) & 3);
  const __bf16* Abase = A + (size_t)(m0 + srow) * K + kb + schunk * 8;
  const __bf16* Bbase = B + (size_t)(n0 + srow) * K + kb + schunk * 8;
  const size_t K128 = (size_t)128 * K;
  __bf16* AsT = &As[t * 8];
  __bf16* BsT = &Bs[t * 8];

  auto stage = [&](const __bf16* base, __bf16* dstT, int kt, int kh) {
    const __bf16* src = base + kt * 64 + kh * 32;
    __bf16* dst = dstT + ((kt & 1) * 2 + kh) * 8192;
    async_copy16(dst, src);
    async_copy16(dst + 4096, src + K128);
  };

  const int gran = (g ^ ((fr >> 1) & 3)) << 3;
  auto rdA = [&](bf16x8* dst, int kt, int kh, int mg) {
    const int ub = ((kt & 1) * 2 + kh) * 256;
    #pragma unroll
    for (int m = 0; m < 4; m++) {
      int row = wr * 128 + (mg * 4 + m) * 16 + fr;
      dst[m] = *(const bf16x8*)&As[(ub + row) * 32 + gran];
    }
  };
  auto rdB = [&](bf16x8* dst, int kt, int kh) {
    const int ub = ((kt & 1) * 2 + kh) * 256;
    #pragma unroll
    for (int n = 0; n < 4; n++) {
      int row = wc * 64 + n * 16 + fr;
      dst[n] = *(const bf16x8*)&Bs[(ub + row) * 32 + gran];
    }
  };

  f32x4 acc[8][4] = {};
  bf16x8 av[4], bX[4], bY[4];

  stage(Abase, AsT, 0, 0); stage(Bbase, BsT, 0, 0);
  stage(Abase, AsT, 0, 1); stage(Bbase, BsT, 0, 1);
  if (NT > 1) { stage(Abase, AsT, 1, 0); stage(Bbase, BsT, 1, 0); }
  asm volatile("s_waitcnt vmcnt(4)" ::: "memory");
  __builtin_amdgcn_s_barrier();

  for (int kt = 0; kt < NT; ++kt) {
    const bool s1 = (kt + 1 < NT), s2 = (kt + 2 < NT);
    rdB(bX, kt, 0);
    rdA(av, kt, 0, 0);
    if (s1) stage(Abase, AsT, kt + 1, 1);
    PHASE_TOP();
    MFMA16(av, bX, 0);
    PHASE_BOT();
    rdA(av, kt, 0, 1);
    if (s1) stage(Bbase, BsT, kt + 1, 1);
    PHASE_TOP();
    MFMA16(av, bX, 1);
    __builtin_amdgcn_s_setprio(0);
    if (s1) { asm volatile("s_waitcnt vmcnt(4)" ::: "memory"); }
    else    { asm volatile("s_waitcnt vmcnt(0)" ::: "memory"); }
    __builtin_amdgcn_s_barrier();
    rdB(bY, kt, 1);
    rdA(av, kt, 1, 0);
    if (s2) stage(Abase, AsT, kt + 2, 0);
    PHASE_TOP();
    MFMA16(av, bY, 0);
    PHASE_BOT();
    rdA(av, kt, 1, 1);
    if (s2) stage(Bbase, BsT, kt + 2, 0);
    PHASE_TOP();
    MFMA16(av, bY, 1);
    PHASE_BOT();
  }

  const size_t zoff = (size_t)z * M * N;
  #pragma unroll
  for (int m = 0; m < 8; m++)
    #pragma unroll
    for (int n = 0; n < 4; n++)
      #pragma unroll
      for (int j = 0; j < 4; j++) {
        int orow = m0 + wr * 128 + m * 16 + g * 4 + j;
        int ocol = n0 + wc * 64 + n * 16 + fr;
        size_t idx = (size_t)orow * N + ocol;
        float v = acc[m][n][j];
        if (EPI == 0) {
          ((__bf16*)Cv)[idx] = (__bf16)v;
        } else if (EPI == 2) {
          ((__bf16*)Cv)[idx] = (__bf16)gelu_tanh(v);
        } else {
          ((__bf16*)Cv)[zoff + idx] = (__bf16)v;
        }
      }
}

// ---------------- 128x256 GEMM, BK=32, ring-3, 2 blocks/CU (R14, used for FC + proj2) ----
template <int EPI>
__global__ __launch_bounds__(512, 4) void gemm128(const __bf16* __restrict__ A,
                                                  const __bf16* __restrict__ B,
                                                  void* __restrict__ Cv,
                                                  int M, int N, int K, int Ksl,
                                                  int NN, int NSPLIT) {
  __shared__ __bf16 As[3][128 * 32];
  __shared__ __bf16 Bs[3][256 * 32];

  const int t = threadIdx.x, w = t >> 6, l = t & 63;
  const int fr = l & 15, g = l >> 4;
  const int wr = w >> 2, wc = w & 3;

  const int nwg = gridDim.x;
  const int wg = (blockIdx.x & 7) * (nwg >> 3) + (blockIdx.x >> 3);
  const int z = wg % NSPLIT;
  const int tile = wg / NSPLIT;
  const int my = tile / NN, nx = tile - my * NN;
  const int m0 = my * 128, n0 = nx * 256;
  const int kb = z * Ksl;
  const int NT = Ksl >> 5;

  const int srow = t >> 2;
  const int schunk = (t & 3) ^ ((t >> 3) & 3);
  const __bf16* Abase = A + (size_t)(m0 + srow) * K + kb + schunk * 8;
  const __bf16* Bbase = B + (size_t)(n0 + srow) * K + kb + schunk * 8;
  const size_t K128 = (size_t)128 * K;

  auto stage = [&](int kt, int slot) {
    const __bf16* sa = Abase + kt * 32;
    const __bf16* sb = Bbase + kt * 32;
    async_copy16(&As[slot][t * 8], sa);
    async_copy16(&Bs[slot][t * 8], sb);
    async_copy16(&Bs[slot][t * 8 + 4096], sb + K128);
  };

  const int gran = (g ^ ((fr >> 1) & 3)) << 3;

  f32x4 acc[4][4] = {};

  stage(0, 0);
  stage(1, 1);
  asm volatile("s_waitcnt vmcnt(3)" ::: "memory");
  __builtin_amdgcn_s_barrier();

  int sc = 0, s1 = 1, s2 = 2;
  for (int kt = 0; kt < NT; ++kt) {
    bf16x8 a[4], b[4];
    #pragma unroll
    for (int m = 0; m < 4; m++)
      a[m] = *(const bf16x8*)&As[sc][(wr * 64 + m * 16 + fr) * 32 + gran];
    #pragma unroll
    for (int n = 0; n < 4; n++)
      b[n] = *(const bf16x8*)&Bs[sc][(wc * 64 + n * 16 + fr) * 32 + gran];
    if (kt + 2 < NT) stage(kt + 2, s2);
    __builtin_amdgcn_s_setprio(1);
    #pragma unroll
    for (int m = 0; m < 4; m++)
      #pragma unroll
      for (int n = 0; n < 4; n++)
        acc[m][n] = __builtin_amdgcn_mfma_f32_16x16x32_bf16(a[m], b[n], acc[m][n], 0, 0, 0);
    __builtin_amdgcn_s_setprio(0);
    if (kt + 1 < NT) {
      if (kt + 2 < NT) { asm volatile("s_waitcnt vmcnt(3)" ::: "memory"); }
      else             { asm volatile("s_waitcnt vmcnt(0)" ::: "memory"); }
    }
    __builtin_amdgcn_s_barrier();
    int tmp = sc; sc = s1; s1 = s2; s2 = tmp;
  }

  const size_t zoff = (size_t)z * M * N;
  #pragma unroll
  for (int m = 0; m < 4; m++)
    #pragma unroll
    for (int n = 0; n < 4; n++)
      #pragma unroll
      for (int j = 0; j < 4; j++) {
        int orow = m0 + wr * 64 + m * 16 + g * 4 + j;
        int ocol = n0 + wc * 64 + n * 16 + fr;
        size_t idx = (size_t)orow * N + ocol;
        float v = acc[m][n][j];
        if (EPI == 0) {
          ((__bf16*)Cv)[idx] = (__bf16)v;
        } else if (EPI == 2) {
          ((__bf16*)Cv)[idx] = (__bf16)gelu_tanh(v);
        } else {
          ((__bf16*)Cv)[zoff + idx] = (__bf16)v;
        }
      }
}

// ---------------- Flash attention (causal), paired q-tiles, 8 waves (R13) ----------------
__global__ __launch_bounds__(512, 2) void attn_kernel(const __bf16* __restrict__ qkv,
                                                      __bf16* __restrict__ out) {
  __shared__ __bf16 Kt[2][64 * 128];
  __shared__ __bf16 Vt[2][64 * 128];
  __shared__ __bf16 Pb[8][16 * 64];

  const int bid = blockIdx.x;
  const int h = bid & 15;
  const int pi = bid >> 4;
  const int qbA = pi, qbB = 31 - pi;

  const int t = threadIdx.x, w = t >> 6, l = t & 63;
  const int g = l >> 4, fr = l & 15;
  const int fkb = g * 8;
  const int myqb = (w < 4) ? qbA : qbB;
  const int q0 = myqb * 64 + (w & 3) * 16;
  const float scale = 0.08838834764831845f; // 1/sqrt(128)

  const int kchunk = fr ^ ((w * 4 + g) & 7);
  const int vkey = (l >> 1) & 3;
  const int vd0  = (l >> 3) * 16 + (l & 1) * 8;

  const size_t row3E = (size_t)(3 * EMB);
  const __bf16* Kg = qkv + EMB + h * HD;
  const __bf16* Vg = qkv + 2 * EMB + h * HD;

  bf16x8 qf[4];
  #pragma unroll
  for (int kc = 0; kc < 4; kc++)
    qf[kc] = *(const bf16x8*)&qkv[(size_t)(q0 + fr) * row3E + h * HD + kc * 32 + fkb];

  f32x4 o[8] = {};
  float mrun[4] = {-1e30f, -1e30f, -1e30f, -1e30f};
  float lsum[4] = {0.f, 0.f, 0.f, 0.f};

  const unsigned vtrb[2] = { lds_addr(&Vt[0][0]) + g * 2048 + fr * 8,
                             lds_addr(&Vt[1][0]) + g * 2048 + fr * 8 };

  auto stage = [&](int buf, int it) {
    const int t0 = it * 64;
    #pragma unroll
    for (int r = 0; r < 2; r++) {
      async_copy16(&Kt[buf][(r * 8 + w) * 512],
                   Kg + (size_t)(t0 + (r * 8 + w) * 4 + g) * row3E + kchunk * 8);
      async_copy16(&Vt[buf][(r * 8 + w) * 512],
                   Vg + (size_t)(t0 + (r * 8 + w) * 4 + vkey) * row3E + vd0);
    }
  };

  const int nt = qbB + 1;
  stage(0, 0);
  int cur = 0;

  for (int it = 0; it < nt; it++) {
    __syncthreads();
    if (it + 1 < nt) stage(cur ^ 1, it + 1);

    if (it <= myqb) {
      const int t0 = it * 64;
      f32x4 s[4] = {};
      __builtin_amdgcn_s_setprio(1);
      #pragma unroll
      for (int n = 0; n < 4; n++)
        #pragma unroll
        for (int kc = 0; kc < 4; kc++) {
          bf16x8 kf = *(const bf16x8*)&Kt[cur][(n * 16 + fr) * 128 +
                                              (((kc * 4 + g) ^ (fr & 7)) << 3)];
          s[n] = __builtin_amdgcn_mfma_f32_16x16x32_bf16(qf[kc], kf, s[n], 0, 0, 0);
        }
      __builtin_amdgcn_s_setprio(0);
      #pragma unroll
      for (int n = 0; n < 4; n++)
        #pragma unroll
        for (int j = 0; j < 4; j++) {
          int tcol = t0 + n * 16 + fr;
          int qrow = q0 + g * 4 + j;
          float v = s[n][j] * scale;
          s[n][j] = (tcol > qrow) ? -1e30f : v;
        }
      float pm[4];
      #pragma unroll
      for (int j = 0; j < 4; j++) {
        pm[j] = fmaxf(fmaxf(s[0][j], s[1][j]), fmaxf(s[2][j], s[3][j]));
        #pragma unroll
        for (int off = 1; off < 16; off <<= 1) pm[j] = fmaxf(pm[j], __shfl_xor(pm[j], off));
      }
      float factor[4];
      #pragma unroll
      for (int j = 0; j < 4; j++) {
        float mn = fmaxf(mrun[j], pm[j]);
        factor[j] = __expf(mrun[j] - mn);
        mrun[j] = mn;
      }
      float rs[4] = {0.f, 0.f, 0.f, 0.f};
      #pragma unroll
      for (int n = 0; n < 4; n++)
        #pragma unroll
        for (int j = 0; j < 4; j++) {
          float p = __expf(s[n][j] - mrun[j]);
          s[n][j] = p;
          rs[j] += p;
        }
      #pragma unroll
      for (int j = 0; j < 4; j++) {
        #pragma unroll
        for (int off = 1; off < 16; off <<= 1) rs[j] += __shfl_xor(rs[j], off);
        lsum[j] = lsum[j] * factor[j] + rs[j];
      }
      #pragma unroll
      for (int b = 0; b < 8; b++)
        #pragma unroll
        for (int j = 0; j < 4; j++) o[b][j] *= factor[j];

      #pragma unroll
      for (int n = 0; n < 4; n++)
        #pragma unroll
        for (int j = 0; j < 4; j++) {
          int q   = g * 4 + j;
          int key = n * 16 + fr;
          int cs  = (key >> 3) ^ (q & 7);
          Pb[w][q * 64 + cs * 8 + (key & 7)] = (__bf16)s[n][j];
        }

      bf16x8 pf[2];
      #pragma unroll
      for (int kc = 0; kc < 2; kc++)
        pf[kc] = *(const bf16x8*)&Pb[w][fr * 64 + (((kc * 4 + g) ^ (fr & 7)) << 3)];

      const unsigned vtr = vtrb[cur];
      __builtin_amdgcn_s_setprio(1);
      #pragma unroll
      for (int b = 0; b < 8; b++) {
        s16x4 t00 = tr16(vtr + b * 128);
        s16x4 t01 = tr16(vtr + b * 128 + 1024);
        s16x4 t10 = tr16(vtr + b * 128 + 8192);
        s16x4 t11 = tr16(vtr + b * 128 + 8192 + 1024);
        asm volatile("s_waitcnt lgkmcnt(0)");
        __builtin_amdgcn_sched_barrier(0);
        union { s16x4 hh[2]; bf16x8 v; } u0, u1;
        u0.hh[0] = t00; u0.hh[1] = t01;
        u1.hh[0] = t10; u1.hh[1] = t11;
        o[b] = __builtin_amdgcn_mfma_f32_16x16x32_bf16(pf[0], u0.v, o[b], 0, 0, 0);
        o[b] = __builtin_amdgcn_mfma_f32_16x16x32_bf16(pf[1], u1.v, o[b], 0, 0, 0);
      }
      __builtin_amdgcn_s_setprio(0);
    }
    cur ^= 1;
  }

  float rcp[4];
  #pragma unroll
  for (int j = 0; j < 4; j++) rcp[j] = 1.0f / lsum[j];
  #pragma unroll
  for (int b = 0; b < 8; b++)
    #pragma unroll
    for (int j = 0; j < 4; j++) {
      int qrow = q0 + g * 4 + j;
      out[(size_t)qrow * EMB + h * HD + b * 16 + fr] = (__bf16)(o[b][j] * rcp[j]);
    }
}

// ---------------- launch ----------------
extern "C" void kernel_launch(void* const* d_in, const int* in_sizes, int n_in,
                              void* d_out, int out_size, void* d_ws, size_t ws_size,
                              hipStream_t stream) {
  const float* x     = (const float*)d_in[0];
  const float* ln1w  = (const float*)d_in[1];
  const float* ln2w  = (const float*)d_in[2];
  const float* wattn = (const float*)d_in[3];
  const float* wproja= (const float*)d_in[4];
  const float* wfc   = (const float*)d_in[5];
  const float* wprojf= (const float*)d_in[6];
  float* out = (float*)d_out;
  char* ws = (char*)d_ws;

  __bf16* wattn_b  = (__bf16*)(ws);                 // 3E*E bf16 = 24 MB
  __bf16* wproja_b = (__bf16*)(ws + 25165824);      // E*E
  __bf16* wfc_b    = (__bf16*)(ws + 33554432);      // 4E*E
  __bf16* wprojf_b = (__bf16*)(ws + 67108864);      // E*4E
  __bf16* h_b      = (__bf16*)(ws + 100663296);     // S*E
  __bf16* qkv_b    = (__bf16*)(ws + 109051904);     // S*3E
  __bf16* attn_b   = (__bf16*)(ws + 134217728);     // S*E
  __bf16* f1_b     = (__bf16*)(ws + 142606336);     // S*4E (33.5 MB)
  __bf16* p1_part  = f1_b;      // proj1 partials: dead before FC writes f1
  __bf16* p2_part  = qkv_b;     // proj2 partials: qkv dead by then

  // all four weight casts in one launch (50,331,648 elems / 1024 per block)
  cast_all<<<49152, 256, 0, stream>>>(wattn, wproja, wfc, wprojf,
                                      wattn_b, wproja_b, wfc_b, wprojf_b);

  ln_kernel<<<S_LEN, 256, 0, stream>>>(x, ln1w, h_b);
  // QKV: [2048, 6144], 192 blocks (gemm256 - R13 best for this shape)
  gemm256<0><<<192, 512, 0, stream>>>(h_b, wattn_b, qkv_b, S_LEN, 3 * EMB, EMB, EMB, 24, 1);
  attn_kernel<<<dim3(256), 512, 0, stream>>>(qkv_b, attn_b);
  // attn proj: split-K x4 -> bf16 partials, 256 blocks (gemm256)
  gemm256<5><<<256, 512, 0, stream>>>(attn_b, wproja_b, p1_part, S_LEN, EMB, EMB, EMB / 4, 8, 4);
  // LN2 fused with partial reduce + residual
  ln_fuse_kernel<<<S_LEN, 256, 0, stream>>>(x, p1_part, ln2w, h_b, out);
  // FC + GELU: [2048, 8192], gemm128 @ 512 blocks (2/CU - R14 best for this shape)
  gemm128<2><<<512, 512, 0, stream>>>(h_b, wfc_b, f1_b, S_LEN, 4 * EMB, EMB, EMB, 32, 1);
  // FFN proj: split-K x4 -> bf16 partials, gemm128 @ 512 blocks
  gemm128<5><<<512, 512, 0, stream>>>(f1_b, wprojf_b, p2_part, S_LEN, EMB, 4 * EMB, 2048, 8, 4);
  // out += sum of partials
  add4_kernel<<<4096, 256, 0, stream>>>(out, p2_part);
}

// Round 16
// 391.367 us; speedup vs baseline: 1.0682x; 1.0569x over previous
//
#include <hip/hip_runtime.h>
#include <hip/hip_bf16.h>

// S=2048, E=2048, H=16, D=128
#define S_LEN 2048
#define EMB   2048
#define NH    16
#define HD    128

typedef __bf16 bf16x8 __attribute__((ext_vector_type(8)));
typedef __bf16 bf16x4 __attribute__((ext_vector_type(4)));
typedef float  f32x4  __attribute__((ext_vector_type(4)));
typedef short  s16x4  __attribute__((ext_vector_type(4)));

__device__ __forceinline__ void async_copy16(void* lds, const void* g) {
  __builtin_amdgcn_global_load_lds((__attribute__((address_space(1))) void*)(void*)g,
                                   (__attribute__((address_space(3))) void*)lds, 16, 0, 0);
}

__device__ __forceinline__ unsigned lds_addr(const void* p) {
  return (unsigned)(uintptr_t)(const __attribute__((address_space(3))) char*)p;
}

__device__ __forceinline__ s16x4 tr16(unsigned addr) {
  s16x4 d;
  asm volatile("ds_read_b64_tr_b16 %0, %1" : "=v"(d) : "v"(addr));
  return d;
}

__device__ __forceinline__ float gelu_tanh(float x) {
  float x3 = x * x * x;
  float t  = 0.7978845608028654f * (x + 0.044715f * x3);
  float th = 1.0f - 2.0f / (__expf(2.0f * t) + 1.0f);
  return 0.5f * x * (1.0f + th);
}

// ---------------- prologue: 4 weight casts + LN1 in ONE launch ----------------
// blocks [0, 49152): cast (1024 elems each, segment-pure);  [49152, 51200): LN1 rows.
__global__ __launch_bounds__(256) void prologue_kernel(const float* __restrict__ s0,
                                                       const float* __restrict__ s1,
                                                       const float* __restrict__ s2,
                                                       const float* __restrict__ s3,
                                                       __bf16* __restrict__ d0,
                                                       __bf16* __restrict__ d1,
                                                       __bf16* __restrict__ d2,
                                                       __bf16* __restrict__ d3,
                                                       const float* __restrict__ x,
                                                       const float* __restrict__ lnw,
                                                       __bf16* __restrict__ lnout) {
  const int t = threadIdx.x;
  if (blockIdx.x < 49152) {
    size_t i = ((size_t)blockIdx.x * 256 + t) * 4;
    const float* s; __bf16* d; size_t off;
    if (i < 12582912ull)       { s = s0; d = d0; off = i; }
    else if (i < 16777216ull)  { s = s1; d = d1; off = i - 12582912ull; }
    else if (i < 33554432ull)  { s = s2; d = d2; off = i - 16777216ull; }
    else                       { s = s3; d = d3; off = i - 33554432ull; }
    float4 v = *(const float4*)(s + off);
    bf16x4 o;
    o[0] = (__bf16)v.x; o[1] = (__bf16)v.y; o[2] = (__bf16)v.z; o[3] = (__bf16)v.w;
    *(bf16x4*)(d + off) = o;
    return;
  }
  // LN1 row
  int row = blockIdx.x - 49152;
  const float* xr = x + (size_t)row * EMB;
  float4 a = *(const float4*)(xr + t * 8);
  float4 b = *(const float4*)(xr + t * 8 + 4);
  float s  = a.x + a.y + a.z + a.w + b.x + b.y + b.z + b.w;
  float sq = a.x*a.x + a.y*a.y + a.z*a.z + a.w*a.w + b.x*b.x + b.y*b.y + b.z*b.z + b.w*b.w;
  #pragma unroll
  for (int o = 32; o > 0; o >>= 1) { s += __shfl_xor(s, o); sq += __shfl_xor(sq, o); }
  __shared__ float red[8];
  if ((t & 63) == 0) { red[t >> 6] = s; red[(t >> 6) + 4] = sq; }
  __syncthreads();
  s  = red[0] + red[1] + red[2] + red[3];
  sq = red[4] + red[5] + red[6] + red[7];
  float mu  = s * (1.0f / EMB);
  float var = sq * (1.0f / EMB) - mu * mu;
  float rs  = rsqrtf(var + 1e-5f);
  float4 w1 = *(const float4*)(lnw + t * 8);
  float4 w2 = *(const float4*)(lnw + t * 8 + 4);
  bf16x8 ov;
  ov[0] = (__bf16)((a.x - mu) * rs * w1.x);
  ov[1] = (__bf16)((a.y - mu) * rs * w1.y);
  ov[2] = (__bf16)((a.z - mu) * rs * w1.z);
  ov[3] = (__bf16)((a.w - mu) * rs * w1.w);
  ov[4] = (__bf16)((b.x - mu) * rs * w2.x);
  ov[5] = (__bf16)((b.y - mu) * rs * w2.y);
  ov[6] = (__bf16)((b.z - mu) * rs * w2.z);
  ov[7] = (__bf16)((b.w - mu) * rs * w2.w);
  *(bf16x8*)(lnout + (size_t)row * EMB + t * 8) = ov;
}

// ---------------- LN2 fused with proj1 split-K reduce + residual ----------------
__global__ __launch_bounds__(256) void ln_fuse_kernel(const float* __restrict__ x,
                                                      const __bf16* __restrict__ part,
                                                      const float* __restrict__ w,
                                                      __bf16* __restrict__ hout,
                                                      float* __restrict__ resout) {
  int row = blockIdx.x;
  int t = threadIdx.x;
  const size_t base = (size_t)row * EMB + t * 8;
  float r[8];
  {
    float4 a = *(const float4*)(x + base);
    float4 b = *(const float4*)(x + base + 4);
    r[0] = a.x; r[1] = a.y; r[2] = a.z; r[3] = a.w;
    r[4] = b.x; r[5] = b.y; r[6] = b.z; r[7] = b.w;
    #pragma unroll
    for (int z = 0; z < 4; z++) {
      bf16x8 p = *(const bf16x8*)(part + (size_t)z * S_LEN * EMB + base);
      #pragma unroll
      for (int k = 0; k < 8; k++) r[k] += (float)p[k];
    }
  }
  float s = 0.f, sq = 0.f;
  #pragma unroll
  for (int k = 0; k < 8; k++) { s += r[k]; sq += r[k] * r[k]; }
  #pragma unroll
  for (int o = 32; o > 0; o >>= 1) { s += __shfl_xor(s, o); sq += __shfl_xor(sq, o); }
  __shared__ float red[8];
  if ((t & 63) == 0) { red[t >> 6] = s; red[(t >> 6) + 4] = sq; }
  __syncthreads();
  s  = red[0] + red[1] + red[2] + red[3];
  sq = red[4] + red[5] + red[6] + red[7];
  float mu  = s * (1.0f / EMB);
  float var = sq * (1.0f / EMB) - mu * mu;
  float rs  = rsqrtf(var + 1e-5f);
  float4 w1 = *(const float4*)(w + t * 8);
  float4 w2 = *(const float4*)(w + t * 8 + 4);
  float wv[8] = {w1.x, w1.y, w1.z, w1.w, w2.x, w2.y, w2.z, w2.w};
  bf16x8 ov;
  #pragma unroll
  for (int k = 0; k < 8; k++) ov[k] = (__bf16)((r[k] - mu) * rs * wv[k]);
  *(bf16x8*)(hout + base) = ov;
  float4 o1 = make_float4(r[0], r[1], r[2], r[3]);
  float4 o2 = make_float4(r[4], r[5], r[6], r[7]);
  *(float4*)(resout + base) = o1;
  *(float4*)(resout + base + 4) = o2;
}

// ---------------- proj2 reduce: out += sum_z part[z] ----------------
__global__ __launch_bounds__(256) void add4_kernel(float* __restrict__ out,
                                                   const __bf16* __restrict__ part) {
  size_t i = ((size_t)blockIdx.x * 256 + threadIdx.x) * 4;
  float4 o = *(const float4*)(out + i);
  #pragma unroll
  for (int z = 0; z < 4; z++) {
    bf16x4 p = *(const bf16x4*)(part + (size_t)z * S_LEN * EMB + i);
    o.x += (float)p[0]; o.y += (float)p[1]; o.z += (float)p[2]; o.w += (float)p[3];
  }
  *(float4*)(out + i) = o;
}

// ---------------- 256x256 8-phase GEMM (R13; QKV, FC, proj2) ----------------
#define MFMA16(AV, BV, MG)                                                                   \
  _Pragma("unroll")                                                                          \
  for (int m = 0; m < 4; m++)                                                                \
    _Pragma("unroll")                                                                        \
    for (int n = 0; n < 4; n++)                                                              \
      acc[(MG) * 4 + m][n] =                                                                 \
          __builtin_amdgcn_mfma_f32_16x16x32_bf16(AV[m], BV[n], acc[(MG) * 4 + m][n], 0, 0, 0);

#define PHASE_TOP()                                                                          \
  __builtin_amdgcn_s_barrier();                                                              \
  __builtin_amdgcn_s_setprio(1);

#define PHASE_BOT()                                                                          \
  __builtin_amdgcn_s_setprio(0);                                                             \
  __builtin_amdgcn_s_barrier();

template <int EPI>
__global__ __launch_bounds__(512, 2) void gemm256(const __bf16* __restrict__ A,
                                                  const __bf16* __restrict__ B,
                                                  void* __restrict__ Cv,
                                                  int M, int N, int K, int Ksl,
                                                  int NN, int NSPLIT) {
  __shared__ __bf16 As[2 * 2 * 256 * 32];
  __shared__ __bf16 Bs[2 * 2 * 256 * 32];

  const int t = threadIdx.x, w = t >> 6, l = t & 63;
  const int fr = l & 15, g = l >> 4;
  const int wr = w >> 2, wc = w & 3;

  const int nwg = gridDim.x;
  const int wg = (blockIdx.x & 7) * (nwg >> 3) + (blockIdx.x >> 3);
  const int z = wg % NSPLIT;
  const int tile = wg / NSPLIT;
  const int my = tile / NN, nx = tile - my * NN;
  const int m0 = my * 256, n0 = nx * 256;
  const int kb = z * Ksl;
  const int NT = Ksl >> 6;

  const int srow = t >> 2;
  const int schunk = (t & 3) ^ ((t >> 3) & 3);
  const __bf16* Abase = A + (size_t)(m0 + srow) * K + kb + schunk * 8;
  const __bf16* Bbase = B + (size_t)(n0 + srow) * K + kb + schunk * 8;
  const size_t K128 = (size_t)128 * K;
  __bf16* AsT = &As[t * 8];
  __bf16* BsT = &Bs[t * 8];

  auto stage = [&](const __bf16* base, __bf16* dstT, int kt, int kh) {
    const __bf16* src = base + kt * 64 + kh * 32;
    __bf16* dst = dstT + ((kt & 1) * 2 + kh) * 8192;
    async_copy16(dst, src);
    async_copy16(dst + 4096, src + K128);
  };

  const int gran = (g ^ ((fr >> 1) & 3)) << 3;
  auto rdA = [&](bf16x8* dst, int kt, int kh, int mg) {
    const int ub = ((kt & 1) * 2 + kh) * 256;
    #pragma unroll
    for (int m = 0; m < 4; m++) {
      int row = wr * 128 + (mg * 4 + m) * 16 + fr;
      dst[m] = *(const bf16x8*)&As[(ub + row) * 32 + gran];
    }
  };
  auto rdB = [&](bf16x8* dst, int kt, int kh) {
    const int ub = ((kt & 1) * 2 + kh) * 256;
    #pragma unroll
    for (int n = 0; n < 4; n++) {
      int row = wc * 64 + n * 16 + fr;
      dst[n] = *(const bf16x8*)&Bs[(ub + row) * 32 + gran];
    }
  };

  f32x4 acc[8][4] = {};
  bf16x8 av[4], bX[4], bY[4];

  stage(Abase, AsT, 0, 0); stage(Bbase, BsT, 0, 0);
  stage(Abase, AsT, 0, 1); stage(Bbase, BsT, 0, 1);
  if (NT > 1) { stage(Abase, AsT, 1, 0); stage(Bbase, BsT, 1, 0); }
  asm volatile("s_waitcnt vmcnt(4)" ::: "memory");
  __builtin_amdgcn_s_barrier();

  for (int kt = 0; kt < NT; ++kt) {
    const bool s1 = (kt + 1 < NT), s2 = (kt + 2 < NT);
    rdB(bX, kt, 0);
    rdA(av, kt, 0, 0);
    if (s1) stage(Abase, AsT, kt + 1, 1);
    PHASE_TOP();
    MFMA16(av, bX, 0);
    PHASE_BOT();
    rdA(av, kt, 0, 1);
    if (s1) stage(Bbase, BsT, kt + 1, 1);
    PHASE_TOP();
    MFMA16(av, bX, 1);
    __builtin_amdgcn_s_setprio(0);
    if (s1) { asm volatile("s_waitcnt vmcnt(4)" ::: "memory"); }
    else    { asm volatile("s_waitcnt vmcnt(0)" ::: "memory"); }
    __builtin_amdgcn_s_barrier();
    rdB(bY, kt, 1);
    rdA(av, kt, 1, 0);
    if (s2) stage(Abase, AsT, kt + 2, 0);
    PHASE_TOP();
    MFMA16(av, bY, 0);
    PHASE_BOT();
    rdA(av, kt, 1, 1);
    if (s2) stage(Bbase, BsT, kt + 2, 0);
    PHASE_TOP();
    MFMA16(av, bY, 1);
    PHASE_BOT();
  }

  const size_t zoff = (size_t)z * M * N;
  #pragma unroll
  for (int m = 0; m < 8; m++)
    #pragma unroll
    for (int n = 0; n < 4; n++)
      #pragma unroll
      for (int j = 0; j < 4; j++) {
        int orow = m0 + wr * 128 + m * 16 + g * 4 + j;
        int ocol = n0 + wc * 64 + n * 16 + fr;
        size_t idx = (size_t)orow * N + ocol;
        float v = acc[m][n][j];
        if (EPI == 0) {
          ((__bf16*)Cv)[idx] = (__bf16)v;
        } else if (EPI == 2) {
          ((__bf16*)Cv)[idx] = (__bf16)gelu_tanh(v);
        } else {
          ((__bf16*)Cv)[zoff + idx] = (__bf16)v;
        }
      }
}

// ---------------- 128x256 GEMM, BK=32, ring-3, 2 blocks/CU (proj1) ----------------
template <int EPI>
__global__ __launch_bounds__(512, 4) void gemm128(const __bf16* __restrict__ A,
                                                  const __bf16* __restrict__ B,
                                                  void* __restrict__ Cv,
                                                  int M, int N, int K, int Ksl,
                                                  int NN, int NSPLIT) {
  __shared__ __bf16 As[3][128 * 32];
  __shared__ __bf16 Bs[3][256 * 32];

  const int t = threadIdx.x, w = t >> 6, l = t & 63;
  const int fr = l & 15, g = l >> 4;
  const int wr = w >> 2, wc = w & 3;

  const int nwg = gridDim.x;
  const int wg = (blockIdx.x & 7) * (nwg >> 3) + (blockIdx.x >> 3);
  const int z = wg % NSPLIT;
  const int tile = wg / NSPLIT;
  const int my = tile / NN, nx = tile - my * NN;
  const int m0 = my * 128, n0 = nx * 256;
  const int kb = z * Ksl;
  const int NT = Ksl >> 5;

  const int srow = t >> 2;
  const int schunk = (t & 3) ^ ((t >> 3) & 3);
  const __bf16* Abase = A + (size_t)(m0 + srow) * K + kb + schunk * 8;
  const __bf16* Bbase = B + (size_t)(n0 + srow) * K + kb + schunk * 8;
  const size_t K128 = (size_t)128 * K;

  auto stage = [&](int kt, int slot) {
    const __bf16* sa = Abase + kt * 32;
    const __bf16* sb = Bbase + kt * 32;
    async_copy16(&As[slot][t * 8], sa);
    async_copy16(&Bs[slot][t * 8], sb);
    async_copy16(&Bs[slot][t * 8 + 4096], sb + K128);
  };

  const int gran = (g ^ ((fr >> 1) & 3)) << 3;

  f32x4 acc[4][4] = {};

  stage(0, 0);
  stage(1, 1);
  asm volatile("s_waitcnt vmcnt(3)" ::: "memory");
  __builtin_amdgcn_s_barrier();

  int sc = 0, s1 = 1, s2 = 2;
  for (int kt = 0; kt < NT; ++kt) {
    bf16x8 a[4], b[4];
    #pragma unroll
    for (int m = 0; m < 4; m++)
      a[m] = *(const bf16x8*)&As[sc][(wr * 64 + m * 16 + fr) * 32 + gran];
    #pragma unroll
    for (int n = 0; n < 4; n++)
      b[n] = *(const bf16x8*)&Bs[sc][(wc * 64 + n * 16 + fr) * 32 + gran];
    if (kt + 2 < NT) stage(kt + 2, s2);
    __builtin_amdgcn_s_setprio(1);
    #pragma unroll
    for (int m = 0; m < 4; m++)
      #pragma unroll
      for (int n = 0; n < 4; n++)
        acc[m][n] = __builtin_amdgcn_mfma_f32_16x16x32_bf16(a[m], b[n], acc[m][n], 0, 0, 0);
    __builtin_amdgcn_s_setprio(0);
    if (kt + 1 < NT) {
      if (kt + 2 < NT) { asm volatile("s_waitcnt vmcnt(3)" ::: "memory"); }
      else             { asm volatile("s_waitcnt vmcnt(0)" ::: "memory"); }
    }
    __builtin_amdgcn_s_barrier();
    int tmp = sc; sc = s1; s1 = s2; s2 = tmp;
  }

  const size_t zoff = (size_t)z * M * N;
  #pragma unroll
  for (int m = 0; m < 4; m++)
    #pragma unroll
    for (int n = 0; n < 4; n++)
      #pragma unroll
      for (int j = 0; j < 4; j++) {
        int orow = m0 + wr * 64 + m * 16 + g * 4 + j;
        int ocol = n0 + wc * 64 + n * 16 + fr;
        size_t idx = (size_t)orow * N + ocol;
        float v = acc[m][n][j];
        if (EPI == 0) {
          ((__bf16*)Cv)[idx] = (__bf16)v;
        } else if (EPI == 2) {
          ((__bf16*)Cv)[idx] = (__bf16)gelu_tanh(v);
        } else {
          ((__bf16*)Cv)[zoff + idx] = (__bf16)v;
        }
      }
}

// ---------------- Flash attention (causal), paired q-tiles, 8 waves (R13) ----------------
__global__ __launch_bounds__(512, 2) void attn_kernel(const __bf16* __restrict__ qkv,
                                                      __bf16* __restrict__ out) {
  __shared__ __bf16 Kt[2][64 * 128];
  __shared__ __bf16 Vt[2][64 * 128];
  __shared__ __bf16 Pb[8][16 * 64];

  const int bid = blockIdx.x;
  const int h = bid & 15;
  const int pi = bid >> 4;
  const int qbA = pi, qbB = 31 - pi;

  const int t = threadIdx.x, w = t >> 6, l = t & 63;
  const int g = l >> 4, fr = l & 15;
  const int fkb = g * 8;
  const int myqb = (w < 4) ? qbA : qbB;
  const int q0 = myqb * 64 + (w & 3) * 16;
  const float scale = 0.08838834764831845f; // 1/sqrt(128)

  const int kchunk = fr ^ ((w * 4 + g) & 7);
  const int vkey = (l >> 1) & 3;
  const int vd0  = (l >> 3) * 16 + (l & 1) * 8;

  const size_t row3E = (size_t)(3 * EMB);
  const __bf16* Kg = qkv + EMB + h * HD;
  const __bf16* Vg = qkv + 2 * EMB + h * HD;

  bf16x8 qf[4];
  #pragma unroll
  for (int kc = 0; kc < 4; kc++)
    qf[kc] = *(const bf16x8*)&qkv[(size_t)(q0 + fr) * row3E + h * HD + kc * 32 + fkb];

  f32x4 o[8] = {};
  float mrun[4] = {-1e30f, -1e30f, -1e30f, -1e30f};
  float lsum[4] = {0.f, 0.f, 0.f, 0.f};

  const unsigned vtrb[2] = { lds_addr(&Vt[0][0]) + g * 2048 + fr * 8,
                             lds_addr(&Vt[1][0]) + g * 2048 + fr * 8 };

  auto stage = [&](int buf, int it) {
    const int t0 = it * 64;
    #pragma unroll
    for (int r = 0; r < 2; r++) {
      async_copy16(&Kt[buf][(r * 8 + w) * 512],
                   Kg + (size_t)(t0 + (r * 8 + w) * 4 + g) * row3E + kchunk * 8);
      async_copy16(&Vt[buf][(r * 8 + w) * 512],
                   Vg + (size_t)(t0 + (r * 8 + w) * 4 + vkey) * row3E + vd0);
    }
  };

  const int nt = qbB + 1;
  stage(0, 0);
  int cur = 0;

  for (int it = 0; it < nt; it++) {
    __syncthreads();
    if (it + 1 < nt) stage(cur ^ 1, it + 1);

    if (it <= myqb) {
      const int t0 = it * 64;
      f32x4 s[4] = {};
      __builtin_amdgcn_s_setprio(1);
      #pragma unroll
      for (int n = 0; n < 4; n++)
        #pragma unroll
        for (int kc = 0; kc < 4; kc++) {
          bf16x8 kf = *(const bf16x8*)&Kt[cur][(n * 16 + fr) * 128 +
                                              (((kc * 4 + g) ^ (fr & 7)) << 3)];
          s[n] = __builtin_amdgcn_mfma_f32_16x16x32_bf16(qf[kc], kf, s[n], 0, 0, 0);
        }
      __builtin_amdgcn_s_setprio(0);
      #pragma unroll
      for (int n = 0; n < 4; n++)
        #pragma unroll
        for (int j = 0; j < 4; j++) {
          int tcol = t0 + n * 16 + fr;
          int qrow = q0 + g * 4 + j;
          float v = s[n][j] * scale;
          s[n][j] = (tcol > qrow) ? -1e30f : v;
        }
      float pm[4];
      #pragma unroll
      for (int j = 0; j < 4; j++) {
        pm[j] = fmaxf(fmaxf(s[0][j], s[1][j]), fmaxf(s[2][j], s[3][j]));
        #pragma unroll
        for (int off = 1; off < 16; off <<= 1) pm[j] = fmaxf(pm[j], __shfl_xor(pm[j], off));
      }
      float factor[4];
      #pragma unroll
      for (int j = 0; j < 4; j++) {
        float mn = fmaxf(mrun[j], pm[j]);
        factor[j] = __expf(mrun[j] - mn);
        mrun[j] = mn;
      }
      float rs[4] = {0.f, 0.f, 0.f, 0.f};
      #pragma unroll
      for (int n = 0; n < 4; n++)
        #pragma unroll
        for (int j = 0; j < 4; j++) {
          float p = __expf(s[n][j] - mrun[j]);
          s[n][j] = p;
          rs[j] += p;
        }
      #pragma unroll
      for (int j = 0; j < 4; j++) {
        #pragma unroll
        for (int off = 1; off < 16; off <<= 1) rs[j] += __shfl_xor(rs[j], off);
        lsum[j] = lsum[j] * factor[j] + rs[j];
      }
      #pragma unroll
      for (int b = 0; b < 8; b++)
        #pragma unroll
        for (int j = 0; j < 4; j++) o[b][j] *= factor[j];

      #pragma unroll
      for (int n = 0; n < 4; n++)
        #pragma unroll
        for (int j = 0; j < 4; j++) {
          int q   = g * 4 + j;
          int key = n * 16 + fr;
          int cs  = (key >> 3) ^ (q & 7);
          Pb[w][q * 64 + cs * 8 + (key & 7)] = (__bf16)s[n][j];
        }

      bf16x8 pf[2];
      #pragma unroll
      for (int kc = 0; kc < 2; kc++)
        pf[kc] = *(const bf16x8*)&Pb[w][fr * 64 + (((kc * 4 + g) ^ (fr & 7)) << 3)];

      const unsigned vtr = vtrb[cur];
      __builtin_amdgcn_s_setprio(1);
      #pragma unroll
      for (int b = 0; b < 8; b++) {
        s16x4 t00 = tr16(vtr + b * 128);
        s16x4 t01 = tr16(vtr + b * 128 + 1024);
        s16x4 t10 = tr16(vtr + b * 128 + 8192);
        s16x4 t11 = tr16(vtr + b * 128 + 8192 + 1024);
        asm volatile("s_waitcnt lgkmcnt(0)");
        __builtin_amdgcn_sched_barrier(0);
        union { s16x4 hh[2]; bf16x8 v; } u0, u1;
        u0.hh[0] = t00; u0.hh[1] = t01;
        u1.hh[0] = t10; u1.hh[1] = t11;
        o[b] = __builtin_amdgcn_mfma_f32_16x16x32_bf16(pf[0], u0.v, o[b], 0, 0, 0);
        o[b] = __builtin_amdgcn_mfma_f32_16x16x32_bf16(pf[1], u1.v, o[b], 0, 0, 0);
      }
      __builtin_amdgcn_s_setprio(0);
    }
    cur ^= 1;
  }

  float rcp[4];
  #pragma unroll
  for (int j = 0; j < 4; j++) rcp[j] = 1.0f / lsum[j];
  #pragma unroll
  for (int b = 0; b < 8; b++)
    #pragma unroll
    for (int j = 0; j < 4; j++) {
      int qrow = q0 + g * 4 + j;
      out[(size_t)qrow * EMB + h * HD + b * 16 + fr] = (__bf16)(o[b][j] * rcp[j]);
    }
}

// ---------------- launch ----------------
extern "C" void kernel_launch(void* const* d_in, const int* in_sizes, int n_in,
                              void* d_out, int out_size, void* d_ws, size_t ws_size,
                              hipStream_t stream) {
  const float* x     = (const float*)d_in[0];
  const float* ln1w  = (const float*)d_in[1];
  const float* ln2w  = (const float*)d_in[2];
  const float* wattn = (const float*)d_in[3];
  const float* wproja= (const float*)d_in[4];
  const float* wfc   = (const float*)d_in[5];
  const float* wprojf= (const float*)d_in[6];
  float* out = (float*)d_out;
  char* ws = (char*)d_ws;

  __bf16* wattn_b  = (__bf16*)(ws);                 // 3E*E bf16 = 24 MB
  __bf16* wproja_b = (__bf16*)(ws + 25165824);      // E*E
  __bf16* wfc_b    = (__bf16*)(ws + 33554432);      // 4E*E
  __bf16* wprojf_b = (__bf16*)(ws + 67108864);      // E*4E
  __bf16* h_b      = (__bf16*)(ws + 100663296);     // S*E
  __bf16* qkv_b    = (__bf16*)(ws + 109051904);     // S*3E
  __bf16* attn_b   = (__bf16*)(ws + 134217728);     // S*E
  __bf16* f1_b     = (__bf16*)(ws + 142606336);     // S*4E (33.5 MB)
  __bf16* p1_part  = f1_b;      // proj1 partials: dead before FC writes f1
  __bf16* p2_part  = qkv_b;     // proj2 partials: qkv dead by then

  // casts (49152 blocks) + LN1 (2048 blocks) in one launch
  prologue_kernel<<<51200, 256, 0, stream>>>(wattn, wproja, wfc, wprojf,
                                             wattn_b, wproja_b, wfc_b, wprojf_b,
                                             x, ln1w, h_b);
  // QKV: [2048, 6144], 192 blocks (gemm256)
  gemm256<0><<<192, 512, 0, stream>>>(h_b, wattn_b, qkv_b, S_LEN, 3 * EMB, EMB, EMB, 24, 1);
  attn_kernel<<<dim3(256), 512, 0, stream>>>(qkv_b, attn_b);
  // attn proj: split-K x4 -> bf16 partials, gemm128 @ 512 blocks (NT=16, 2/CU)
  gemm128<5><<<512, 512, 0, stream>>>(attn_b, wproja_b, p1_part, S_LEN, EMB, EMB, EMB / 4, 8, 4);
  // LN2 fused with partial reduce + residual
  ln_fuse_kernel<<<S_LEN, 256, 0, stream>>>(x, p1_part, ln2w, h_b, out);
  // FC + GELU: [2048, 8192], gemm256 @ 256 blocks (R13 best total config)
  gemm256<2><<<256, 512, 0, stream>>>(h_b, wfc_b, f1_b, S_LEN, 4 * EMB, EMB, EMB, 32, 1);
  // FFN proj: split-K x4 -> bf16 partials, gemm256 @ 256 blocks
  gemm256<5><<<256, 512, 0, stream>>>(f1_b, wprojf_b, p2_part, S_LEN, EMB, 4 * EMB, 2048, 8, 4);
  // out += sum of partials
  add4_kernel<<<4096, 256, 0, stream>>>(out, p2_part);
}